// Round 1
// baseline (620.199 us; speedup 1.0000x reference)
//
#include <hip/hip_runtime.h>

typedef _Float16 f16x8 __attribute__((ext_vector_type(8)));
typedef float f32x4 __attribute__((ext_vector_type(4)));

#define Dd 256
#define Hh 1024

// ---------- prep: pack weights fragment-major (unchanged) ----------
// W1P tile (w,nt,kk) = ((w*8+nt)*8+kk): lane(q*16+ln)*8+j holds
//   W1[kk*32+q*8+j][w*128+nt*16+ln]  (B-fragment for 16x16x32 MFMA)
__global__ void pack_w1_kernel(const float* __restrict__ W1, _Float16* __restrict__ W1P) {
    int gid = blockIdx.x * 256 + threadIdx.x;       // 256*1024 elements
    int h = gid & 1023, d = gid >> 10;
    int w = h >> 7, nt = (h >> 4) & 7, ln = h & 15;
    int kk = d >> 5, q = (d >> 3) & 3, j = d & 7;
    W1P[(((w * 8 + nt) * 8 + kk) * 64 + q * 16 + ln) * 8 + j] = (_Float16)W1[d * 1024 + h];
}
// W2P tile (w,kk,t) = ((w*32+kk)*2+t): consumption-linear for GEMM2
__global__ void pack_w2_kernel(const float* __restrict__ W2, _Float16* __restrict__ W2P) {
    int gid = blockIdx.x * 256 + threadIdx.x;       // 1024*256 elements
    int dcol = gid & 255, h = gid >> 8;
    int w = dcol >> 5, t = (dcol >> 4) & 1, ln = dcol & 15;
    int kk = h >> 5, q = (h >> 3) & 3, j = h & 7;
    W2P[(((w * 32 + kk) * 2 + t) * 64 + q * 16 + ln) * 8 + j] = (_Float16)W2[h * 256 + dcol];
}

// ---------------- main: 64 blocks x 512 thr, register weight ring ----------------
// Block owns 16 batch rows, whole solve, zero inter-block sync. Wave w owns
// H-slice [w*128,+128) (GEMM1) and D-slice [w*32,+32) (GEMM2). Weights are NOT
// shared between waves, so they never touch LDS: each wave streams 32 chunks
// (4 KB = 4 fragment tiles of 16 B/lane) per eval DIRECTLY global->VGPR into an
// 8-slot register ring (prefetch distance 5). RAW/WAR on the ring is register
// dataflow — the compiler emits exact counted s_waitcnt vmcnt(N); no manual
// guards needed. Barriers are raw lgkmcnt(0)+s_barrier (LDS-only hazards: act,
// z), so weight prefetch stays in flight across them, including the cross-eval
// wraparound prefetch of the next eval's chunks 0..4 issued during GEMM2.
__global__ __launch_bounds__(512, 2) void ode_kernel(
    const float* __restrict__ z0, const float* __restrict__ tv,
    const float* __restrict__ b1, const float* __restrict__ b2,
    const _Float16* __restrict__ W1P, const _Float16* __restrict__ W2P,
    float* __restrict__ out) {
    __shared__ _Float16 act_lds[16][1032];   // 33 KB (+8 pad)
    __shared__ _Float16 z_lds[16][264];      // 8.25 KB

    const int tid  = threadIdx.x;
    const int w    = tid >> 6;
    const int lane = tid & 63;
    const int ln   = lane & 15;
    const int q    = lane >> 4;
    const int m0   = blockIdx.x * 16;

    const float h = (tv[1] - tv[0]) * 0.125f;

    float bb1[8];
#pragma unroll
    for (int nt = 0; nt < 8; ++nt) bb1[nt] = b1[w * 128 + nt * 16 + ln];
    float bb2v[2];
#pragma unroll
    for (int t = 0; t < 2; ++t) bb2v[t] = b2[w * 32 + t * 16 + ln];

    const _Float16* W1w = W1P + (size_t)(w * 64) * 512;   // 64 KB: tiles (nt,kk)
    const _Float16* W2w = W2P + (size_t)(w * 64) * 512;   // 64 KB: tiles (kk,t)

    // 8-slot register ring: 8 x 4 x f16x8 = 128 VGPRs. Chunk cc (mod 32) lands
    // in slot cc&7; distance-5 issue means slot (c+5)&7 last held chunk c-3,
    // consumed 3 iterations ago — safe. 32 % 8 == 0 keeps slot assignment
    // eval-invariant across the #pragma unroll 1 backedge.
    f16x8 wb[8][4];

#define ISSUE(cc) { const int cm = (cc) & 31;                                        \
    const _Float16* gsrc = (cm < 16) ? (W1w + cm * 2048) : (W2w + (cm - 16) * 2048); \
    _Pragma("unroll")                                                                \
    for (int ii = 0; ii < 4; ++ii)                                                   \
        wb[(cc) & 7][ii] = *(const f16x8*)(gsrc + ii * 512 + lane * 8); }

// act/z are LDS-only: lgkmcnt(0) publishes ds_writes, s_barrier syncs waves.
// Deliberately NO vmcnt drain — weight prefetch loads stay in flight.
#define BARRIER() asm volatile("s_waitcnt lgkmcnt(0)\n\ts_barrier" ::: "memory")

    // RK4 state in registers (C-layout): z[t][r] = z[m0+q*4+r][w*32+t*16+ln]
    f32x4 z[2], zsum[2];
#pragma unroll
    for (int t = 0; t < 2; ++t)
#pragma unroll
        for (int r = 0; r < 4; ++r)
            z[t][r] = z0[(m0 + q * 4 + r) * Dd + w * 32 + t * 16 + ln];
#pragma unroll
    for (int t = 0; t < 2; ++t)
#pragma unroll
        for (int r = 0; r < 4; ++r)
            z_lds[q * 4 + r][w * 32 + t * 16 + ln] = (_Float16)z[t][r];
    __syncthreads();   // full drain once; prologue prefetch issued after it

    ISSUE(0); ISSUE(1); ISSUE(2); ISSUE(3); ISSUE(4);

#pragma unroll 1
    for (int ev = 0; ev < 32; ++ev) {
        const int e = ev & 3;

        // ---- GEMM1: act[:, w*128..+128) = tanh(z @ W1 + b1) ----
        f16x8 a1[8];
#pragma unroll
        for (int kk = 0; kk < 8; ++kk)
            a1[kk] = *(const f16x8*)&z_lds[ln][kk * 32 + q * 8];

#pragma unroll
        for (int nt = 0; nt < 8; ++nt) {
            f32x4 acc = {0.f, 0.f, 0.f, 0.f};
#pragma unroll
            for (int half = 0; half < 2; ++half) {
                const int c = nt * 2 + half;      // chunk: tiles kk = half*4..+3
                ISSUE(c + 5);                     // c=11..15 issue W2 chunks 16..20
#pragma unroll
                for (int i = 0; i < 4; ++i)
                    acc = __builtin_amdgcn_mfma_f32_16x16x32_f16(
                        a1[half * 4 + i], wb[c & 7][i], acc, 0, 0, 0);
            }
#pragma unroll
            for (int r = 0; r < 4; ++r) {
                float x = acc[r] + bb1[nt];
                float ex = __expf(2.0f * x);
                act_lds[q * 4 + r][w * 128 + nt * 16 + ln] =
                    (_Float16)(1.0f - 2.0f / (ex + 1.0f));
            }
        }
        BARRIER();   // act visible; W2 chunks 16..20 remain in flight

        // ---- GEMM2: k[:, w*32..+32) = act @ W2 + b2 ----
        f32x4 acc2[2] = {{0.f, 0.f, 0.f, 0.f}, {0.f, 0.f, 0.f, 0.f}};
#pragma unroll
        for (int cp = 0; cp < 16; ++cp) {
            const int c = 16 + cp;               // chunk: kk pair {2cp,2cp+1} x t{0,1}
            ISSUE(c + 5);                        // cp>=11 wraps: next eval chunks 0..4
#pragma unroll
            for (int half = 0; half < 2; ++half) {
                const int kk = cp * 2 + half;
                f16x8 a2 = *(const f16x8*)&act_lds[ln][kk * 32 + q * 8];
#pragma unroll
                for (int t = 0; t < 2; ++t)
                    acc2[t] = __builtin_amdgcn_mfma_f32_16x16x32_f16(
                        a2, wb[c & 7][half * 2 + t], acc2[t], 0, 0, 0);
            }
        }

        // ---- RK4 epilogue (registers) ----
#pragma unroll
        for (int t = 0; t < 2; ++t) {
            f32x4 kv, za;
#pragma unroll
            for (int r = 0; r < 4; ++r) kv[r] = acc2[t][r] + bb2v[t];
            if (e == 0) {
                zsum[t] = kv;
            } else if (e == 3) {
#pragma unroll
                for (int r = 0; r < 4; ++r) zsum[t][r] += kv[r];
            } else {
#pragma unroll
                for (int r = 0; r < 4; ++r) zsum[t][r] += 2.0f * kv[r];
            }
            if (e < 3) {
                const float c = (e == 2) ? h : 0.5f * h;
#pragma unroll
                for (int r = 0; r < 4; ++r) za[r] = z[t][r] + c * kv[r];
            } else {
#pragma unroll
                for (int r = 0; r < 4; ++r) {
                    z[t][r] += (h * (1.0f / 6.0f)) * zsum[t][r];
                    za[r] = z[t][r];
                }
            }
#pragma unroll
            for (int r = 0; r < 4; ++r)
                z_lds[q * 4 + r][w * 32 + t * 16 + ln] = (_Float16)za[r];
        }
        BARRIER();   // z visible for next eval; wraparound prefetch in flight
    }

#pragma unroll
    for (int t = 0; t < 2; ++t)
#pragma unroll
        for (int r = 0; r < 4; ++r)
            out[(m0 + q * 4 + r) * Dd + w * 32 + t * 16 + ln] = z[t][r];
#undef ISSUE
#undef BARRIER
}

extern "C" void kernel_launch(void* const* d_in, const int* in_sizes, int n_in,
                              void* d_out, int out_size, void* d_ws, size_t ws_size,
                              hipStream_t stream) {
    const float* z0 = (const float*)d_in[0];
    const float* tv = (const float*)d_in[1];
    const float* W1 = (const float*)d_in[2];   // [256][1024]
    const float* b1 = (const float*)d_in[3];   // [1024]
    const float* W2 = (const float*)d_in[4];   // [1024][256]
    const float* b2 = (const float*)d_in[5];   // [256]
    float* out = (float*)d_out;

    _Float16* W1P = (_Float16*)d_ws;           // 512 KB fragment-major
    _Float16* W2P = W1P + Hh * Dd;             // 512 KB fragment-major

    pack_w1_kernel<<<1024, 256, 0, stream>>>(W1, W1P);
    pack_w2_kernel<<<1024, 256, 0, stream>>>(W2, W2P);

    ode_kernel<<<64, 512, 0, stream>>>(z0, tv, b1, b2, W1P, W2P, out);
}

// Round 2
// 525.394 us; speedup vs baseline: 1.1804x; 1.1804x over previous
//
#include <hip/hip_runtime.h>

typedef _Float16 f16x8 __attribute__((ext_vector_type(8)));
typedef float f32x4 __attribute__((ext_vector_type(4)));

#define Dd 256
#define Hh 1024

// ---------- prep: pack weights fragment-major (unchanged) ----------
// W1P tile (w,nt,kk) = ((w*8+nt)*8+kk): lane(q*16+ln)*8+j holds
//   W1[kk*32+q*8+j][w*128+nt*16+ln]  (B-fragment for 16x16x32 MFMA)
__global__ void pack_w1_kernel(const float* __restrict__ W1, _Float16* __restrict__ W1P) {
    int gid = blockIdx.x * 256 + threadIdx.x;       // 256*1024 elements
    int h = gid & 1023, d = gid >> 10;
    int w = h >> 7, nt = (h >> 4) & 7, ln = h & 15;
    int kk = d >> 5, q = (d >> 3) & 3, j = d & 7;
    W1P[(((w * 8 + nt) * 8 + kk) * 64 + q * 16 + ln) * 8 + j] = (_Float16)W1[d * 1024 + h];
}
// W2P tile (w,kk,t) = ((w*32+kk)*2+t): consumption-linear for GEMM2
__global__ void pack_w2_kernel(const float* __restrict__ W2, _Float16* __restrict__ W2P) {
    int gid = blockIdx.x * 256 + threadIdx.x;       // 1024*256 elements
    int dcol = gid & 255, h = gid >> 8;
    int w = dcol >> 5, t = (dcol >> 4) & 1, ln = dcol & 15;
    int kk = h >> 5, q = (h >> 3) & 3, j = h & 7;
    W2P[(((w * 32 + kk) * 2 + t) * 64 + q * 16 + ln) * 8 + j] = (_Float16)W2[h * 256 + dcol];
}

// ---------------- main: 64 blocks x 512 thr, 4-slot register weight ring ----------------
// Block owns 16 batch rows, whole solve, zero inter-block sync. Wave w owns
// H-slice [w*128,+128) (GEMM1) and D-slice [w*32,+32) (GEMM2). Weights are
// per-wave private, so they bypass LDS entirely: each wave streams 32 chunks
// (4 KB = 4 fragment tiles of 16 B/lane) per eval global->VGPR into a 4-slot
// register ring (64 VGPRs), issue-after-consume => steady-state depth 4
// (16 KB/wave in flight). Round-1 lesson: an 8-slot ring (128 VGPRs) blew the
// 256-VGPR cap of __launch_bounds__(512,2) -> spill + load-sinking, regression.
// 4 slots keeps total demand ~180 VGPRs. A single sched_barrier(0) after each
// ISSUE pins the loads at their issue point so the scheduler cannot sink them
// toward their uses (which would collapse the prefetch distance). RAW on the
// ring is plain register dataflow: the compiler emits exact counted
// s_waitcnt vmcnt(N); WAR (loads overwriting the slot just consumed) is a HW
// scoreboard interlock. Barriers are raw lgkmcnt(0)+s_barrier (LDS-only
// hazards: act, z), so weight prefetch stays in flight across them, including
// the wraparound prefetch of the next eval's chunks 0..3 issued during GEMM2.
__global__ __launch_bounds__(512, 2) void ode_kernel(
    const float* __restrict__ z0, const float* __restrict__ tv,
    const float* __restrict__ b1, const float* __restrict__ b2,
    const _Float16* __restrict__ W1P, const _Float16* __restrict__ W2P,
    float* __restrict__ out) {
    __shared__ _Float16 act_lds[16][1032];   // 33 KB (+8 pad)
    __shared__ _Float16 z_lds[16][264];      // 8.25 KB

    const int tid  = threadIdx.x;
    const int w    = tid >> 6;
    const int lane = tid & 63;
    const int ln   = lane & 15;
    const int q    = lane >> 4;
    const int m0   = blockIdx.x * 16;

    const float h = (tv[1] - tv[0]) * 0.125f;

    float bb1[8];
#pragma unroll
    for (int nt = 0; nt < 8; ++nt) bb1[nt] = b1[w * 128 + nt * 16 + ln];
    float bb2v[2];
#pragma unroll
    for (int t = 0; t < 2; ++t) bb2v[t] = b2[w * 32 + t * 16 + ln];

    const _Float16* W1w = W1P + (size_t)(w * 64) * 512;   // 64 KB: tiles (nt,kk)
    const _Float16* W2w = W2P + (size_t)(w * 64) * 512;   // 64 KB: tiles (kk,t)

    // 4-slot register ring: 4 x 4 x f16x8 = 64 VGPRs. Chunk cc (mod 32) lands
    // in slot cc&3. Issue-after-consume: when chunk c is being waited on,
    // chunks c..c+3 are in flight (all 4 slots distinct); ISSUE(c+4) reuses
    // the slot consumed this iteration. 32 % 4 == 0 keeps slot assignment
    // eval-invariant across the #pragma unroll 1 backedge.
    f16x8 wb[4][4];

#define ISSUE(cc) { const int cm = (cc) & 31;                                        \
    const _Float16* gsrc = (cm < 16) ? (W1w + cm * 2048) : (W2w + (cm - 16) * 2048); \
    _Pragma("unroll")                                                                \
    for (int ii = 0; ii < 4; ++ii)                                                   \
        wb[(cc) & 3][ii] = *(const f16x8*)(gsrc + ii * 512 + lane * 8);              \
    __builtin_amdgcn_sched_barrier(0); }

// act/z are LDS-only: lgkmcnt(0) publishes ds_writes, s_barrier syncs waves.
// Deliberately NO vmcnt drain — weight prefetch loads stay in flight.
#define BARRIER() asm volatile("s_waitcnt lgkmcnt(0)\n\ts_barrier" ::: "memory")

    // RK4 state in registers (C-layout): z[t][r] = z[m0+q*4+r][w*32+t*16+ln]
    f32x4 z[2], zsum[2];
#pragma unroll
    for (int t = 0; t < 2; ++t)
#pragma unroll
        for (int r = 0; r < 4; ++r)
            z[t][r] = z0[(m0 + q * 4 + r) * Dd + w * 32 + t * 16 + ln];
#pragma unroll
    for (int t = 0; t < 2; ++t)
#pragma unroll
        for (int r = 0; r < 4; ++r)
            z_lds[q * 4 + r][w * 32 + t * 16 + ln] = (_Float16)z[t][r];
    __syncthreads();   // full drain once; prologue prefetch issued after it

    ISSUE(0); ISSUE(1); ISSUE(2); ISSUE(3);

#pragma unroll 1
    for (int ev = 0; ev < 32; ++ev) {
        const int e = ev & 3;

        // ---- GEMM1: act[:, w*128..+128) = tanh(z @ W1 + b1) ----
        f16x8 a1[8];
#pragma unroll
        for (int kk = 0; kk < 8; ++kk)
            a1[kk] = *(const f16x8*)&z_lds[ln][kk * 32 + q * 8];

#pragma unroll
        for (int nt = 0; nt < 8; ++nt) {
            f32x4 acc = {0.f, 0.f, 0.f, 0.f};
#pragma unroll
            for (int half = 0; half < 2; ++half) {
                const int c = nt * 2 + half;      // chunk: tiles kk = half*4..+3
#pragma unroll
                for (int i = 0; i < 4; ++i)
                    acc = __builtin_amdgcn_mfma_f32_16x16x32_f16(
                        a1[half * 4 + i], wb[c & 3][i], acc, 0, 0, 0);
                ISSUE(c + 4);                     // c=12..15 issue W2 chunks 16..19
            }
#pragma unroll
            for (int r = 0; r < 4; ++r) {
                float x = acc[r] + bb1[nt];
                float ex = __expf(2.0f * x);
                act_lds[q * 4 + r][w * 128 + nt * 16 + ln] =
                    (_Float16)(1.0f - 2.0f / (ex + 1.0f));
            }
        }
        BARRIER();   // act visible; W2 chunks 16..19 remain in flight

        // ---- GEMM2: k[:, w*32..+32) = act @ W2 + b2 ----
        f32x4 acc2[2] = {{0.f, 0.f, 0.f, 0.f}, {0.f, 0.f, 0.f, 0.f}};
#pragma unroll
        for (int cp = 0; cp < 16; ++cp) {
            const int c = 16 + cp;               // chunk: kk pair {2cp,2cp+1} x t{0,1}
#pragma unroll
            for (int half = 0; half < 2; ++half) {
                const int kk = cp * 2 + half;
                f16x8 a2 = *(const f16x8*)&act_lds[ln][kk * 32 + q * 8];
#pragma unroll
                for (int t = 0; t < 2; ++t)
                    acc2[t] = __builtin_amdgcn_mfma_f32_16x16x32_f16(
                        a2, wb[c & 3][half * 2 + t], acc2[t], 0, 0, 0);
            }
            ISSUE(c + 4);                        // cp>=12 wraps: next eval chunks 0..3
        }

        // ---- RK4 epilogue (registers) ----
#pragma unroll
        for (int t = 0; t < 2; ++t) {
            f32x4 kv, za;
#pragma unroll
            for (int r = 0; r < 4; ++r) kv[r] = acc2[t][r] + bb2v[t];
            if (e == 0) {
                zsum[t] = kv;
            } else if (e == 3) {
#pragma unroll
                for (int r = 0; r < 4; ++r) zsum[t][r] += kv[r];
            } else {
#pragma unroll
                for (int r = 0; r < 4; ++r) zsum[t][r] += 2.0f * kv[r];
            }
            if (e < 3) {
                const float c = (e == 2) ? h : 0.5f * h;
#pragma unroll
                for (int r = 0; r < 4; ++r) za[r] = z[t][r] + c * kv[r];
            } else {
#pragma unroll
                for (int r = 0; r < 4; ++r) {
                    z[t][r] += (h * (1.0f / 6.0f)) * zsum[t][r];
                    za[r] = z[t][r];
                }
            }
#pragma unroll
            for (int r = 0; r < 4; ++r)
                z_lds[q * 4 + r][w * 32 + t * 16 + ln] = (_Float16)za[r];
        }
        BARRIER();   // z visible for next eval; wraparound prefetch in flight
    }

#pragma unroll
    for (int t = 0; t < 2; ++t)
#pragma unroll
        for (int r = 0; r < 4; ++r)
            out[(m0 + q * 4 + r) * Dd + w * 32 + t * 16 + ln] = z[t][r];
#undef ISSUE
#undef BARRIER
}

extern "C" void kernel_launch(void* const* d_in, const int* in_sizes, int n_in,
                              void* d_out, int out_size, void* d_ws, size_t ws_size,
                              hipStream_t stream) {
    const float* z0 = (const float*)d_in[0];
    const float* tv = (const float*)d_in[1];
    const float* W1 = (const float*)d_in[2];   // [256][1024]
    const float* b1 = (const float*)d_in[3];   // [1024]
    const float* W2 = (const float*)d_in[4];   // [1024][256]
    const float* b2 = (const float*)d_in[5];   // [256]
    float* out = (float*)d_out;

    _Float16* W1P = (_Float16*)d_ws;           // 512 KB fragment-major
    _Float16* W2P = W1P + Hh * Dd;             // 512 KB fragment-major

    pack_w1_kernel<<<1024, 256, 0, stream>>>(W1, W1P);
    pack_w2_kernel<<<1024, 256, 0, stream>>>(W2, W2P);

    ode_kernel<<<64, 512, 0, stream>>>(z0, tv, b1, b2, W1P, W2P, out);
}